// Round 3
// baseline (447.361 us; speedup 1.0000x reference)
//
#include <hip/hip_runtime.h>

// =============================================================================
// QuantumContrastiveModel — reduction: circuit is unitary, cancels in fidelity.
//   fid = clip((ua.ub)^2/(max(|ua|,1e-8)max(|ub|,1e-8))^2,0,1), u=tanh(relu(xW1+b1)W2+b2)
// R1: 170us — latency bound. R2: +prefetch, 166us — no change.
// Diagnosis: A-fragment direct loads = 128-B DRAM granules, 16 rows/instr,
//   stride 3136 -> ~16% HBM efficiency (measured 1.3 TB/s). MLP can't fix.
// R3: LDS-staged GEMM: 512-B contiguous bursts per row-chunk, fp32->bf16 in
//   register, fragment-order LDS (XOR swizzle), MFMA reads b128 conflict-free.
// =============================================================================

#define KDIM 784
#define HDIM 64
#define KC 128
#define NFULL 6                  // 6*128 = 768, tail = 16 floats
#define KSTEP_B 1040             // 64 slots * 16 B + 16 pad
#define TILE_B (4 * KSTEP_B)     // 4 ksteps per chunk per tile
#define MAT_B  (4 * TILE_B)      // 4 tiles (64 rows)
#define SMEM_BYTES (2 * MAT_B)   // 33280; lds_h overlay needs 18432 <= this

#define KSTEPS 25
#define W1S_ELEMS (KSTEPS * 4 * 64 * 8)
#define W1S_BYTES (W1S_ELEMS * 2)

typedef float  f32x4  __attribute__((ext_vector_type(4)));
typedef short  bf16x8 __attribute__((ext_vector_type(8)));
typedef short  bf16x4 __attribute__((ext_vector_type(4)));

__device__ __forceinline__ unsigned short f2bf(float f) {
  unsigned u = __float_as_uint(f);
  u += 0x7fffu + ((u >> 16) & 1u);       // RNE
  return (unsigned short)(u >> 16);
}
__device__ __forceinline__ float bf2f(unsigned short h) {
  return __uint_as_float(((unsigned)h) << 16);
}
__device__ __forceinline__ bf16x8 cvt8(f32x4 lo, f32x4 hi) {
  bf16x8 r;
  r[0] = (short)f2bf(lo[0]); r[1] = (short)f2bf(lo[1]);
  r[2] = (short)f2bf(lo[2]); r[3] = (short)f2bf(lo[3]);
  r[4] = (short)f2bf(hi[0]); r[5] = (short)f2bf(hi[1]);
  r[6] = (short)f2bf(hi[2]); r[7] = (short)f2bf(hi[3]);
  return r;
}
__device__ __forceinline__ bf16x4 cvt4(f32x4 v) {
  bf16x4 r;
  r[0] = (short)f2bf(v[0]); r[1] = (short)f2bf(v[1]);
  r[2] = (short)f2bf(v[2]); r[3] = (short)f2bf(v[3]);
  return r;
}
__device__ __forceinline__ float tanh_fast(float x) {
  float e = __expf(2.0f * x);
  return 1.0f - 2.0f / (e + 1.0f);
}

// --- prep: W1 -> bf16 MFMA B-fragment order (K padded to 800); W2 -> 16x64 T.
__global__ __launch_bounds__(256)
void prep_kernel(const float* __restrict__ W1, const float* __restrict__ W2,
                 unsigned short* __restrict__ w1s, float* __restrict__ w2t) {
  int tid = blockIdx.x * 256 + threadIdx.x;
  if (tid < W1S_ELEMS) {
    int j  = tid & 7;
    int l  = (tid >> 3) & 63;
    int st = tid >> 9;
    int s  = st >> 2;
    int t  = st & 3;
    int k  = s * 32 + (l >> 4) * 8 + j;
    int n  = t * 16 + (l & 15);
    float v = (k < KDIM) ? W1[k * HDIM + n] : 0.0f;
    w1s[tid] = f2bf(v);
  }
  if (tid < HDIM * 16) {
    int c = tid >> 6;
    int k = tid & 63;
    w2t[c * HDIM + k] = W2[k * 16 + c];
  }
}

__global__ __launch_bounds__(256, 3)
void qcm_kernel(const float* __restrict__ img_a, const float* __restrict__ img_b,
                const float* __restrict__ b1,    const float* __restrict__ b2,
                const unsigned short* __restrict__ w1s,
                const float* __restrict__ w2t,
                float* __restrict__ out) {
  __shared__ __attribute__((aligned(16))) char smem[SMEM_BYTES];

  const int tid  = threadIdx.x;
  const int wave = tid >> 6;
  const int lane = tid & 63;
  const int row0 = blockIdx.x * 64;

  // staging thread mapping (full chunks): row r = p*16 + (tid>>4), tile=p,
  // m=tid>>4; float offset fo=(tid&15)*8 -> kstep s, quad q.
  const int sm   = tid >> 4;               // m (row within tile)
  const int su   = tid & 15;
  const int ss   = su >> 2;                // kstep within chunk
  const int sq   = su & 3;                 // quad
  const int sfo  = su * 8;                 // float offset in chunk
  const int wslot = ((sq * 16 + sm) ^ (ss << 2) ^ sq) * 16;
  const int wbase = ss * KSTEP_B;

  f32x4 rg[16];

  // ---- load chunk 0
  {
    const float* pa = img_a + (size_t)(row0 + sm) * KDIM + sfo;
    const float* pb = img_b + (size_t)(row0 + sm) * KDIM + sfo;
    #pragma unroll
    for (int p = 0; p < 4; ++p) {
      rg[p*4+0] = *(const f32x4*)(pa + p * 16 * KDIM);
      rg[p*4+1] = *(const f32x4*)(pa + p * 16 * KDIM + 4);
      rg[p*4+2] = *(const f32x4*)(pb + p * 16 * KDIM);
      rg[p*4+3] = *(const f32x4*)(pb + p * 16 * KDIM + 4);
    }
  }

  f32x4 accA[4], accB[4];
  #pragma unroll
  for (int t = 0; t < 4; ++t) {
    accA[t][0]=accA[t][1]=accA[t][2]=accA[t][3]=0.0f;
    accB[t][0]=accB[t][1]=accB[t][2]=accB[t][3]=0.0f;
  }

  const int4* bwl = (const int4*)w1s + lane;
  const int qlane = lane >> 4;

  for (int c = 0; c < NFULL; ++c) {
    // ---- cvt + LDS write (chunk c)
    #pragma unroll
    for (int p = 0; p < 4; ++p) {
      char* d = smem + p * TILE_B + wbase + wslot;
      *(bf16x8*)(d)         = cvt8(rg[p*4+0], rg[p*4+1]);
      *(bf16x8*)(d + MAT_B) = cvt8(rg[p*4+2], rg[p*4+3]);
    }
    __syncthreads();

    // ---- issue loads for next chunk (or tail) before MFMA
    if (c < NFULL - 1) {
      const float* pa = img_a + (size_t)(row0 + sm) * KDIM + (c + 1) * KC + sfo;
      const float* pb = img_b + (size_t)(row0 + sm) * KDIM + (c + 1) * KC + sfo;
      #pragma unroll
      for (int p = 0; p < 4; ++p) {
        rg[p*4+0] = *(const f32x4*)(pa + p * 16 * KDIM);
        rg[p*4+1] = *(const f32x4*)(pa + p * 16 * KDIM + 4);
        rg[p*4+2] = *(const f32x4*)(pb + p * 16 * KDIM);
        rg[p*4+3] = *(const f32x4*)(pb + p * 16 * KDIM + 4);
      }
    } else {
      // tail: 16 floats (cols 768..784) — thread t: row tid>>2, sub tid&3
      const int tr = tid >> 2, sub = tid & 3;
      rg[0] = *(const f32x4*)(img_a + (size_t)(row0 + tr) * KDIM + 768 + sub * 4);
      rg[1] = *(const f32x4*)(img_b + (size_t)(row0 + tr) * KDIM + 768 + sub * 4);
    }

    // ---- MFMA over 4 ksteps from LDS
    const char* abase = smem + wave * TILE_B;
    #pragma unroll
    for (int s = 0; s < 4; ++s) {
      const int slot = (lane ^ (s << 2) ^ qlane) * 16;
      bf16x8 fa = *(const bf16x8*)(abase + s * KSTEP_B + slot);
      bf16x8 fb = *(const bf16x8*)(abase + MAT_B + s * KSTEP_B + slot);
      const int4* bp = bwl + (c * 4 + s) * 256;
      int4 w0 = bp[0], w1 = bp[64], w2 = bp[128], w3 = bp[192];
      accA[0] = __builtin_amdgcn_mfma_f32_16x16x32_bf16(fa, __builtin_bit_cast(bf16x8, w0), accA[0], 0, 0, 0);
      accB[0] = __builtin_amdgcn_mfma_f32_16x16x32_bf16(fb, __builtin_bit_cast(bf16x8, w0), accB[0], 0, 0, 0);
      accA[1] = __builtin_amdgcn_mfma_f32_16x16x32_bf16(fa, __builtin_bit_cast(bf16x8, w1), accA[1], 0, 0, 0);
      accB[1] = __builtin_amdgcn_mfma_f32_16x16x32_bf16(fb, __builtin_bit_cast(bf16x8, w1), accB[1], 0, 0, 0);
      accA[2] = __builtin_amdgcn_mfma_f32_16x16x32_bf16(fa, __builtin_bit_cast(bf16x8, w2), accA[2], 0, 0, 0);
      accB[2] = __builtin_amdgcn_mfma_f32_16x16x32_bf16(fb, __builtin_bit_cast(bf16x8, w2), accB[2], 0, 0, 0);
      accA[3] = __builtin_amdgcn_mfma_f32_16x16x32_bf16(fa, __builtin_bit_cast(bf16x8, w3), accA[3], 0, 0, 0);
      accB[3] = __builtin_amdgcn_mfma_f32_16x16x32_bf16(fb, __builtin_bit_cast(bf16x8, w3), accB[3], 0, 0, 0);
    }
    __syncthreads();
  }

  // ---- tail chunk: write 16 valid floats + zero quads 2,3; 1 kstep (S=24)
  {
    const int tr = tid >> 2, sub = tid & 3;
    const int tm = tr & 15, ttile = tr >> 4;
    const int tq = sub >> 1, jh = sub & 1;
    const int tslot = ((tq * 16 + tm) ^ tq) * 16 + jh * 8;
    char* d = smem + ttile * TILE_B + tslot;
    *(bf16x4*)(d)         = cvt4(rg[0]);
    *(bf16x4*)(d + MAT_B) = cvt4(rg[1]);
    // zeros: 2 mats x 4 tiles x 32 slots(quads 2,3) = 256 x 16B
    const int zm = tid >> 7, zt = (tid >> 5) & 3, zs = tid & 31;
    const int zl = 32 + zs;
    const int zslot = (zl ^ (zl >> 4)) * 16;
    int4 zero; zero.x = zero.y = zero.z = zero.w = 0;
    *(int4*)(smem + zm * MAT_B + zt * TILE_B + zslot) = zero;
  }
  __syncthreads();
  {
    const char* abase = smem + wave * TILE_B;
    const int slot = (lane ^ qlane) * 16;
    bf16x8 fa = *(const bf16x8*)(abase + slot);
    bf16x8 fb = *(const bf16x8*)(abase + MAT_B + slot);
    const int4* bp = bwl + 24 * 256;
    int4 w0 = bp[0], w1 = bp[64], w2 = bp[128], w3 = bp[192];
    accA[0] = __builtin_amdgcn_mfma_f32_16x16x32_bf16(fa, __builtin_bit_cast(bf16x8, w0), accA[0], 0, 0, 0);
    accB[0] = __builtin_amdgcn_mfma_f32_16x16x32_bf16(fb, __builtin_bit_cast(bf16x8, w0), accB[0], 0, 0, 0);
    accA[1] = __builtin_amdgcn_mfma_f32_16x16x32_bf16(fa, __builtin_bit_cast(bf16x8, w1), accA[1], 0, 0, 0);
    accB[1] = __builtin_amdgcn_mfma_f32_16x16x32_bf16(fb, __builtin_bit_cast(bf16x8, w1), accB[1], 0, 0, 0);
    accA[2] = __builtin_amdgcn_mfma_f32_16x16x32_bf16(fa, __builtin_bit_cast(bf16x8, w2), accA[2], 0, 0, 0);
    accB[2] = __builtin_amdgcn_mfma_f32_16x16x32_bf16(fb, __builtin_bit_cast(bf16x8, w2), accB[2], 0, 0, 0);
    accA[3] = __builtin_amdgcn_mfma_f32_16x16x32_bf16(fa, __builtin_bit_cast(bf16x8, w3), accA[3], 0, 0, 0);
    accB[3] = __builtin_amdgcn_mfma_f32_16x16x32_bf16(fb, __builtin_bit_cast(bf16x8, w3), accB[3], 0, 0, 0);
  }
  __syncthreads();   // LDS reads done; safe to overlay lds_h

  // ---- epilogue: bias+relu, h -> LDS bf16 (overlay)
  unsigned short (*lds_h)[72] = (unsigned short (*)[72])smem;
  const int m = lane & 15;
  const int quad = lane >> 4;
  #pragma unroll
  for (int t = 0; t < 4; ++t) {
    float bias = b1[t * 16 + m];
    const int ra = wave * 32;
    #pragma unroll
    for (int j = 0; j < 4; ++j) {
      float ha = fmaxf(accA[t][j] + bias, 0.0f);
      float hb = fmaxf(accB[t][j] + bias, 0.0f);
      lds_h[ra +      quad * 4 + j][t * 16 + m] = f2bf(ha);
      lds_h[ra + 16 + quad * 4 + j][t * 16 + m] = f2bf(hb);
    }
  }
  __syncthreads();

  // ---- phase 2: 4 threads/pair, 64->16 GEMM + tanh + normalized dot
  const int p = tid >> 2;
  const int q = tid & 3;
  const int wsrc = p >> 4;
  const int r = p & 15;
  const unsigned short* ha_row = &lds_h[wsrc * 32 + r][0];
  const unsigned short* hb_row = &lds_h[wsrc * 32 + 16 + r][0];

  float za[4], zb[4];
  #pragma unroll
  for (int i = 0; i < 4; ++i) { za[i] = b2[q * 4 + i]; zb[i] = za[i]; }

  for (int k = 0; k < HDIM; k += 4) {
    uint2 ua = *(const uint2*)(ha_row + k);
    uint2 ub = *(const uint2*)(hb_row + k);
    float a0 = bf2f((unsigned short)(ua.x & 0xffff));
    float a1 = bf2f((unsigned short)(ua.x >> 16));
    float a2 = bf2f((unsigned short)(ua.y & 0xffff));
    float a3 = bf2f((unsigned short)(ua.y >> 16));
    float b0v = bf2f((unsigned short)(ub.x & 0xffff));
    float b1v = bf2f((unsigned short)(ub.x >> 16));
    float b2v = bf2f((unsigned short)(ub.y & 0xffff));
    float b3v = bf2f((unsigned short)(ub.y >> 16));
    #pragma unroll
    for (int i = 0; i < 4; ++i) {
      f32x4 wv = *(const f32x4*)(w2t + (q * 4 + i) * HDIM + k);
      za[i] += a0 * wv[0] + a1 * wv[1] + a2 * wv[2] + a3 * wv[3];
      zb[i] += b0v * wv[0] + b1v * wv[1] + b2v * wv[2] + b3v * wv[3];
    }
  }

  float d = 0.0f, na2 = 0.0f, nb2 = 0.0f;
  #pragma unroll
  for (int i = 0; i < 4; ++i) {
    float ua = tanh_fast(za[i]);
    float ub = tanh_fast(zb[i]);
    d += ua * ub; na2 += ua * ua; nb2 += ub * ub;
  }
  d   += __shfl_xor(d, 1);   d   += __shfl_xor(d, 2);
  na2 += __shfl_xor(na2, 1); na2 += __shfl_xor(na2, 2);
  nb2 += __shfl_xor(nb2, 1); nb2 += __shfl_xor(nb2, 2);

  if (q == 0) {
    float den = fmaxf(sqrtf(na2), 1e-8f) * fmaxf(sqrtf(nb2), 1e-8f);
    float ov = d / den;
    out[blockIdx.x * 64 + p] = fminf(ov * ov, 1.0f);
  }
}

extern "C" void kernel_launch(void* const* d_in, const int* in_sizes, int n_in,
                              void* d_out, int out_size, void* d_ws, size_t ws_size,
                              hipStream_t stream) {
  const float* img_a = (const float*)d_in[0];
  const float* img_b = (const float*)d_in[1];
  const float* W1    = (const float*)d_in[2];
  const float* b1    = (const float*)d_in[3];
  const float* W2    = (const float*)d_in[4];
  const float* b2    = (const float*)d_in[5];
  // d_in[6] = theta: unused — unitary circuit cancels in fidelity.

  unsigned short* w1s = (unsigned short*)d_ws;
  float* w2t = (float*)((char*)d_ws + W1S_BYTES);

  prep_kernel<<<(W1S_ELEMS + 255) / 256, 256, 0, stream>>>(W1, W2, w1s, w2t);

  const int n_pairs = out_size;   // 65536
  qcm_kernel<<<n_pairs / 64, 256, 0, stream>>>(img_a, img_b, b1, b2, w1s, w2t,
                                               (float*)d_out);
}